// Round 14
// baseline (107.679 us; speedup 1.0000x reference)
//
#include <hip/hip_runtime.h>
#include <hip/hip_bf16.h>

#define M 8192
#define N 8192
#define K 512
#define BM 128
#define BN 128
#define BK 32
#define NT (K / BK)  // 16 K-steps
#define EPAD 132     // epilogue LDS row stride (floats)

typedef __attribute__((ext_vector_type(8))) short bf16x8;
typedef __attribute__((ext_vector_type(4))) float f32x4;
typedef __attribute__((ext_vector_type(8))) unsigned short us8;

__device__ inline void gload_lds16(const void* g, void* l) {
  __builtin_amdgcn_global_load_lds(
      (const __attribute__((address_space(1))) unsigned int*)g,
      (__attribute__((address_space(3))) unsigned int*)l, 16, 0, 0);
}

#define BARRIER()                          \
  do {                                     \
    asm volatile("" ::: "memory");         \
    __builtin_amdgcn_s_barrier();          \
    asm volatile("" ::: "memory");         \
  } while (0)

#define BARRIER_LGKM()                                 \
  do {                                                 \
    asm volatile("s_waitcnt lgkmcnt(0)" ::: "memory"); \
    __builtin_amdgcn_s_barrier();                      \
    asm volatile("" ::: "memory");                     \
  } while (0)

// Fused prep: cast f32 rows -> bf16, store INVERSE L2 norm (1/max(norm,1e-4)).
__global__ __launch_bounds__(256) void prep_kernel(const float* __restrict__ img,
                                                   const float* __restrict__ txt,
                                                   unsigned short* __restrict__ Abf,
                                                   unsigned short* __restrict__ Bbf,
                                                   float* __restrict__ w1,
                                                   float* __restrict__ w2) {
  const int half = blockIdx.x >> 11;
  const int lb = blockIdx.x & 2047;
  const float* in = half ? txt : img;
  unsigned short* outb = half ? Bbf : Abf;
  float* norms = half ? w2 : w1;

  const int gw = (lb * 256 + threadIdx.x) >> 6;
  const int lane = threadIdx.x & 63;
  const float4* rp4 = (const float4*)(in + (size_t)gw * K);
  float4 v0 = rp4[lane * 2];
  float4 v1 = rp4[lane * 2 + 1];
  float ss = v0.x * v0.x + v0.y * v0.y + v0.z * v0.z + v0.w * v0.w +
             v1.x * v1.x + v1.y * v1.y + v1.z * v1.z + v1.w * v1.w;
  float f[8] = {v0.x, v0.y, v0.z, v0.w, v1.x, v1.y, v1.z, v1.w};
  us8 o;
#pragma unroll
  for (int i = 0; i < 8; ++i) {
    __hip_bfloat16 b = __float2bfloat16(f[i]);
    o[i] = *(unsigned short*)&b;
  }
  *(us8*)(outb + (size_t)gw * K + lane * 8) = o;
#pragma unroll
  for (int off = 32; off > 0; off >>= 1) ss += __shfl_down(ss, off, 64);
  if (lane == 0) norms[gw] = 1.0f / fmaxf(sqrtf(ss), 1e-4f);
}

// 128x128 bf16 GEMM. Change vs r13: A AND B triple-buffered, both staged
// at distance 2 (issue loads for t+2 at step t); vmcnt(4) at step end only
// requires loads issued a FULL step earlier (~1000+ cyc) -> HBM latency
// covered, no per-step stall. LDS 48 KB -> 3 blocks/CU.
__global__ __launch_bounds__(256, 4) void gemm_kernel(const unsigned short* __restrict__ A,
                                                      const unsigned short* __restrict__ B,
                                                      const float* __restrict__ iw1,
                                                      const float* __restrict__ iw2,
                                                      float* __restrict__ C) {
  // 48 KB pool: 3x8KB A bufs + 3x8KB B bufs; epilogue tile (33.8 KB) overlaid.
  __shared__ __align__(16) char smem[6 * BM * BK * 2];
  auto AsP = [&](int buf) { return (unsigned short*)(smem + buf * BM * BK * 2); };
  auto BsP = [&](int buf) { return (unsigned short*)(smem + (3 + buf) * BM * BK * 2); };
  float* eps = (float*)smem;

  const int tid = threadIdx.x;
  const int wave = tid >> 6;  // 0..3
  const int lane = tid & 63;
  const int wr = wave >> 1;
  const int wc = wave & 1;
  const int fr = lane & 15;
  const int fq = lane >> 4;

  // Two-level swizzle: xcd owns col-panels [xcd*8, xcd*8+8).
  const int xcd = blockIdx.x & 7;
  const int idx = blockIdx.x >> 3;
  const int bRow = (idx >> 3) * BM;
  const int bCol = (xcd * 8 + (idx & 7)) * BN;

  // Staging: 16 rows x 64B per wave per call; source granule pre-swizzled
  // so LDS slot jl holds global granule jl ^ ((row>>1)&3)  (rule #21).
  const int srow = lane >> 2;
  const int scol = (((lane & 3) ^ ((srow >> 1) & 3)) * 8);

  auto stageA = [&](int buf, int kt) {
#pragma unroll
    for (int c = 0; c < 2; ++c)
      gload_lds16(A + (size_t)(bRow + c * 64 + wave * 16 + srow) * K + kt * BK + scol,
                  (char*)AsP(buf) + (c * 64 + wave * 16) * 64);
  };
  auto stageB = [&](int buf, int kt) {
#pragma unroll
    for (int c = 0; c < 2; ++c)
      gload_lds16(B + (size_t)(bCol + c * 64 + wave * 16 + srow) * K + kt * BK + scol,
                  (char*)BsP(buf) + (c * 64 + wave * 16) * 64);
  };
  auto ldA = [&](int buf, int r) -> bf16x8 {
    return *(const bf16x8*)((const char*)AsP(buf) + r * 64 + ((fq ^ ((r >> 1) & 3)) * 16));
  };
  auto ldB = [&](int buf, int r) -> bf16x8 {
    return *(const bf16x8*)((const char*)BsP(buf) + r * 64 + ((fq ^ ((r >> 1) & 3)) * 16));
  };

  f32x4 acc[4][4] = {};

  // Prologue: stage (A,B) for steps 0 and 1; need step-0 data landed.
  stageA(0, 0);
  stageB(0, 0);
  stageA(1, 1);
  stageB(1, 1);
  asm volatile("s_waitcnt vmcnt(4)" ::: "memory");  // A0,B0 done; A1,B1 in flight
  BARRIER();

#pragma unroll
  for (int t = 0; t < NT; ++t) {
    const int cur = t % 3;

    if (t + 2 < NT) {  // 4 gloads for step t+2 (distance-2 prefetch)
      const int b2 = (t + 2) % 3;
      stageA(b2, t + 2);
      stageB(b2, t + 2);
    }

    bf16x8 a[4], b[4];
#pragma unroll
    for (int m = 0; m < 4; ++m) a[m] = ldA(cur, wr * 64 + m * 16 + fr);
#pragma unroll
    for (int n = 0; n < 4; ++n) b[n] = ldB(cur, wc * 64 + n * 16 + fr);

    __builtin_amdgcn_s_setprio(1);
#pragma unroll
    for (int m = 0; m < 4; ++m)
#pragma unroll
      for (int n = 0; n < 4; ++n)
        acc[m][n] = __builtin_amdgcn_mfma_f32_16x16x32_bf16(a[m], b[n], acc[m][n], 0, 0, 0);
    __builtin_amdgcn_s_setprio(0);

    if (t < NT - 2) {
      // Outstanding: [A(t+1)B(t+1) x4][A(t+2)B(t+2) x4] -> vmcnt(4) lands
      // t+1's data (issued a full step ago), leaves t+2's 4 in flight.
      asm volatile("s_waitcnt vmcnt(4)" ::: "memory");
    } else if (t == NT - 2) {
      asm volatile("s_waitcnt vmcnt(0)" ::: "memory");
    }
    BARRIER();
  }

  // Norm scales. C/D layout: col = lane&15, row = (lane>>4)*4 + reg.
  float i1v[4][4], i2v[4];
#pragma unroll
  for (int m = 0; m < 4; ++m)
#pragma unroll
    for (int r = 0; r < 4; ++r) i1v[m][r] = iw1[bRow + wr * 64 + m * 16 + fq * 4 + r];
#pragma unroll
  for (int n = 0; n < 4; ++n) i2v[n] = iw2[bCol + wc * 64 + n * 16 + fr];

  // Full-line epilogue (r13): two 64-row halves through LDS, f32x4 stores.
  const int erow = tid >> 5;
  const int ecol = (tid & 31) * 4;
#pragma unroll
  for (int h = 0; h < 2; ++h) {
    BARRIER_LGKM();
#pragma unroll
    for (int dm = 0; dm < 2; ++dm) {
      const int m = 2 * h + dm;
#pragma unroll
      for (int n = 0; n < 4; ++n) {
        f32x4 v = acc[m][n];
        const int lc = wc * 64 + n * 16 + fr;
#pragma unroll
        for (int r = 0; r < 4; ++r) {
          const int lr = wr * 32 + dm * 16 + fq * 4 + r;
          eps[lr * EPAD + lc] = v[r] * i1v[m][r] * i2v[n];
        }
      }
    }
    BARRIER_LGKM();
#pragma unroll
    for (int p = 0; p < 8; ++p) {
      const int lr = p * 8 + erow;
      f32x4 v = *(const f32x4*)&eps[lr * EPAD + ecol];
      const int gRow = bRow + (lr >> 5) * 64 + (2 * h + ((lr >> 4) & 1)) * 16 + (lr & 15);
      *(f32x4*)&C[(size_t)gRow * N + bCol + ecol] = v;
    }
  }
}

extern "C" void kernel_launch(void* const* d_in, const int* in_sizes, int n_in,
                              void* d_out, int out_size, void* d_ws, size_t ws_size,
                              hipStream_t stream) {
  (void)in_sizes; (void)n_in; (void)out_size; (void)ws_size;
  const float* img = (const float*)d_in[0];
  const float* txt = (const float*)d_in[1];
  float* out = (float*)d_out;

  unsigned short* Abf = (unsigned short*)d_ws;
  unsigned short* Bbf = Abf + (size_t)M * K;
  float* w1 = (float*)(Bbf + (size_t)N * K);
  float* w2 = w1 + M;

  prep_kernel<<<4096, 256, 0, stream>>>(img, txt, Abf, Bbf, w1, w2);
  gemm_kernel<<<(M / BM) * (N / BN), 256, 0, stream>>>(Abf, Bbf, w1, w2, out);
}